// Round 1
// baseline (318.407 us; speedup 1.0000x reference)
//
#include <hip/hip_runtime.h>

// Problem constants
#define BATCH 8
#define CIN   128
#define HH    112
#define WW    112
#define COUT  256
#define KOFF  18          // 2*K*K offset channels
#define HW    (HH*WW)     // 12544
#define NPIX  (BATCH*HW)  // 100352
#define BK    64          // K-step (bf16 elems)

typedef __attribute__((ext_vector_type(8))) short short8;
typedef __attribute__((ext_vector_type(4))) float f32x4;

__device__ __forceinline__ unsigned short f2bf(float f) {
    union { float f; unsigned u; } v; v.f = f;
    unsigned r = v.u + 0x7fffu + ((v.u >> 16) & 1u);   // round-to-nearest-even
    return (unsigned short)(r >> 16);
}
__device__ __forceinline__ float bflo(unsigned u) {
    union { unsigned u; float f; } v; v.u = u << 16; return v.f;
}
__device__ __forceinline__ float bfhi(unsigned u) {
    union { unsigned u; float f; } v; v.u = u & 0xffff0000u; return v.f;
}

// async global -> LDS, 16B per lane. LDS dest must be wave-uniform base;
// HW writes base + lane*16. Global src is per-lane (zero-page redirect ok).
__device__ __forceinline__ void gload16(const unsigned short* g, unsigned short* l) {
    __builtin_amdgcn_global_load_lds(
        (const __attribute__((address_space(1))) void*)g,
        (__attribute__((address_space(3))) void*)l, 16, 0, 0);
}

// ---------------------------------------------------------------------------
// Kernel 0z: zero scratch page used as DMA source for invalid (out-of-image)
// tap rows in the gload_lds staging.
// ---------------------------------------------------------------------------
__global__ void zfill_kernel(unsigned short* z) { z[threadIdx.x] = 0; }

// ---------------------------------------------------------------------------
// Kernel 0a: main weights: wt[co][t*128+ci] = bf16(cw[co][ci][t])
// ---------------------------------------------------------------------------
__global__ __launch_bounds__(256) void wconvert_kernel(
    const float* __restrict__ cw, unsigned short* __restrict__ wt)
{
    const int i  = blockIdx.x * 256 + threadIdx.x;   // 1152*256 == 294912 exact
    const int co = i / 1152;
    const int k  = i % 1152;
    const int t  = k >> 7;
    const int ci = k & 127;
    wt[i] = f2bf(cw[((size_t)(co * CIN + ci)) * 9 + t]);
}

// ---------------------------------------------------------------------------
// Kernel 0b: offset weights, N padded 18->32: owt[co][t*128+ci], rows>=18 zero
// ---------------------------------------------------------------------------
__global__ __launch_bounds__(256) void owconvert_kernel(
    const float* __restrict__ ow, unsigned short* __restrict__ owt)
{
    const int i  = blockIdx.x * 256 + threadIdx.x;   // 144*256 == 36864 exact
    const int co = i / 1152;
    const int k  = i % 1152;
    const int t  = k >> 7;
    const int ci = k & 127;
    owt[i] = (co < KOFF) ? f2bf(ow[((size_t)(co * CIN + ci)) * 9 + t]) : 0;
}

// ---------------------------------------------------------------------------
// Kernel 0c: x NCHW fp32 -> NHWC bf16 (xh[p][128]) via LDS transpose.
// ---------------------------------------------------------------------------
__global__ __launch_bounds__(256) void nhwc_kernel(
    const float* __restrict__ x, unsigned short* __restrict__ xh)
{
    __shared__ unsigned int sm[64 * 65];
    const int tid = threadIdx.x;
    const int px  = tid & 63;
    const int cig = tid >> 6;
    const int p0  = blockIdx.x * 64;          // 1568 blocks; never straddles b
    const int b   = p0 / HW;
    const int rem0 = p0 % HW;
    const float* xb = x + (size_t)b * CIN * HW + rem0 + px;

    const int c0 = 2 * cig;
#pragma unroll
    for (int k = 0; k < 16; ++k) {
        const int ci = c0 + 8 * k;
        const float a0 = xb[(size_t)ci * HW];
        const float a1 = xb[(size_t)(ci + 1) * HW];
        sm[px * 65 + (ci >> 1)] = (unsigned)f2bf(a0) | ((unsigned)f2bf(a1) << 16);
    }
    __syncthreads();

    const int row = tid >> 2, chunk = tid & 3;
    unsigned int u[16];
#pragma unroll
    for (int c = 0; c < 16; ++c) u[c] = sm[row * 65 + chunk * 16 + c];
    uint4* gv = (uint4*)(xh + ((size_t)(p0 + row)) * 128 + chunk * 32);
#pragma unroll
    for (int j = 0; j < 4; ++j) {
        uint4 t; t.x = u[4*j]; t.y = u[4*j+1]; t.z = u[4*j+2]; t.w = u[4*j+3];
        gv[j] = t;
    }
}

// ---------------------------------------------------------------------------
// Kernel 1: offset conv as implicit-GEMM MFMA. M=128 px, N=32 (18 used),
// K=1152. A staged via global_load_lds (zero-page redirect for invalid taps);
// B = owt (always valid). D -> LDS -> packed bf16 (oy,ox) pairs po[p*9+s].
// ---------------------------------------------------------------------------
__global__ __launch_bounds__(256) void offset_mfma_kernel(
    const unsigned short* __restrict__ xh, const unsigned short* __restrict__ owt,
    const float* __restrict__ ob, const unsigned short* __restrict__ zbuf,
    unsigned int* __restrict__ po)
{
    __shared__ __align__(16) unsigned short As[128 * BK];    // 16 KB linear
    __shared__ __align__(16) unsigned short Bs[32 * BK];     // 4 KB linear
    __shared__ float sm_off[128][20];                        // 10.2 KB
    __shared__ float sb_bias[KOFF];

    const int tid  = threadIdx.x;
    const int lane = tid & 63;
    const int wave = tid >> 6;
    const int mb   = blockIdx.x;         // 784 blocks (98/image)
    const int b    = mb / 98;
    const int p0   = (mb % 98) * 128;

    if (tid < KOFF) sb_bias[tid] = ob[tid];

    // staging geometry: wave w, A-instr j: rows w*32 + j*8 + (lane>>3), 16B chunk lane&7
    const int rlane = lane >> 3;
    const int chunk = lane & 7;

    const unsigned short* xb = xh + (size_t)b * HW * 128;

    int py4[4], px4[4];
    const unsigned short* asrc0[4];
#pragma unroll
    for (int j = 0; j < 4; ++j) {
        const int row = wave * 32 + j * 8 + rlane;
        const int pp  = p0 + row;
        py4[j] = pp / WW;
        px4[j] = pp % WW;
        asrc0[j] = xb + (size_t)pp * 128 + chunk * 8;
    }
    // B: 32 rows total -> 1 gload per wave: rows wave*8 + rlane
    const unsigned short* bsrc0 = owt + (size_t)(wave * 8 + rlane) * 1152 + chunk * 8;
    const unsigned short* zsrc  = zbuf + chunk * 8;

    const int col  = lane & 15;
    const int quad = lane >> 4;
    const int m0   = wave * 32;          // wave owns 32 M-rows, all 32 N-cols

    f32x4 acc[2][2];
#pragma unroll
    for (int i = 0; i < 2; ++i)
#pragma unroll
        for (int j = 0; j < 2; ++j) acc[i][j] = (f32x4)0.f;

    for (int t = 0; t < 9; ++t) {
        const int dy = t / 3 - 1, dx = t % 3 - 1;
        const int tcol = t * 128;
        bool valid[4];
        const unsigned short* atv[4];
#pragma unroll
        for (int j = 0; j < 4; ++j) {
            valid[j] = ((unsigned)(py4[j] + dy) < HH) && ((unsigned)(px4[j] + dx) < WW);
            atv[j]   = asrc0[j] + (dy * WW + dx) * 128;
        }

#pragma unroll
        for (int ci0 = 0; ci0 < 128; ci0 += BK) {
            __syncthreads();   // previous frags consumed before DMA overwrites
#pragma unroll
            for (int j = 0; j < 4; ++j)
                gload16(valid[j] ? atv[j] + ci0 : zsrc, As + (wave * 32 + j * 8) * BK);
            gload16(bsrc0 + tcol + ci0, Bs + (wave * 8) * BK);
            __syncthreads();   // compiler drains vmcnt(0) before s_barrier

#pragma unroll
            for (int kk = 0; kk < BK; kk += 32) {
                short8 af[2], bfr[2];
#pragma unroll
                for (int f = 0; f < 2; ++f)
                    af[f] = *(const short8*)(As + (m0 + f * 16 + col) * BK + kk + quad * 8);
#pragma unroll
                for (int f = 0; f < 2; ++f)
                    bfr[f] = *(const short8*)(Bs + (f * 16 + col) * BK + kk + quad * 8);
#pragma unroll
                for (int fm = 0; fm < 2; ++fm)
#pragma unroll
                    for (int fn = 0; fn < 2; ++fn)
                        acc[fm][fn] = __builtin_amdgcn_mfma_f32_16x16x32_bf16(
                            af[fm], bfr[fn], acc[fm][fn], 0, 0, 0);
            }
        }
    }

    // D (row = m0+fm*16+quad*4+r, col = fn*16+(lane&15)) -> LDS
#pragma unroll
    for (int fm = 0; fm < 2; ++fm)
#pragma unroll
        for (int fn = 0; fn < 2; ++fn) {
            const int c = fn * 16 + col;
            if (c < KOFF) {
                const int rb = m0 + fm * 16 + quad * 4;
#pragma unroll
                for (int r = 0; r < 4; ++r) sm_off[rb + r][c] = acc[fm][fn][r];
            }
        }
    __syncthreads();

    if (tid < 128) {
        unsigned int* pop = po + ((size_t)(b * HW + p0 + tid)) * 9;
#pragma unroll
        for (int s = 0; s < 9; ++s) {
            const float oy = sm_off[tid][s]     + sb_bias[s];
            const float ox = sm_off[tid][9 + s] + sb_bias[9 + s];
            pop[s] = (unsigned)f2bf(oy) | ((unsigned)f2bf(ox) << 16);
        }
    }
}

// ---------------------------------------------------------------------------
// Kernel 2: deformable sampling on NHWC bf16 -> NHWC bf16 (unchanged).
// ---------------------------------------------------------------------------
__global__ __launch_bounds__(256) void sample2_kernel(
    const unsigned short* __restrict__ xh, const unsigned int* __restrict__ po,
    unsigned short* __restrict__ sampled)
{
    const int tid  = threadIdx.x;
    const int lane = tid & 63;
    const int wave = tid >> 6;
    const int ppx  = lane >> 4;
    const int cl   = lane & 15;
    const int p    = blockIdx.x * 16 + wave * 4 + ppx;   // 6272 blocks * 16 == NPIX
    const int b    = p / HW;
    const int rem  = p % HW;
    const int y    = rem / WW;
    const int xx   = rem % WW;

    int   idx[9][4];
    float wt[9][4];
    const unsigned int* pop = po + (size_t)p * 9;
#pragma unroll
    for (int s = 0; s < 9; ++s) {
        const int ky = s / 3, kx = s % 3;
        const unsigned u = pop[s];
        const float oy = bflo(u);
        const float ox = bfhi(u);
        const float sy = (float)(y + ky - 1) + oy;
        const float sx = (float)(xx + kx - 1) + ox;
        const float y0f = floorf(sy), x0f = floorf(sx);
        const int   y0 = (int)y0f, x0 = (int)x0f;
        const float wy1 = sy - y0f, wx1 = sx - x0f;
        const float wy0 = 1.f - wy1, wx0 = 1.f - wx1;
        const int y0c = min(max(y0, 0), HH - 1), y1c = min(max(y0 + 1, 0), HH - 1);
        const int x0c = min(max(x0, 0), WW - 1), x1c = min(max(x0 + 1, 0), WW - 1);
        const bool vy0 = (unsigned)y0 < HH, vy1 = (unsigned)(y0 + 1) < HH;
        const bool vx0 = (unsigned)x0 < WW, vx1 = (unsigned)(x0 + 1) < WW;
        idx[s][0] = y0c * WW + x0c; wt[s][0] = (vy0 && vx0) ? wy0 * wx0 : 0.f;
        idx[s][1] = y0c * WW + x1c; wt[s][1] = (vy0 && vx1) ? wy0 * wx1 : 0.f;
        idx[s][2] = y1c * WW + x0c; wt[s][2] = (vy1 && vx0) ? wy1 * wx0 : 0.f;
        idx[s][3] = y1c * WW + x1c; wt[s][3] = (vy1 && vx1) ? wy1 * wx1 : 0.f;
    }

    const unsigned short* xb = xh + ((size_t)b * HW) * 128 + cl * 8;
    float acc[8];
#pragma unroll
    for (int j = 0; j < 8; ++j) acc[j] = 0.f;

#pragma unroll
    for (int s = 0; s < 9; ++s) {
#pragma unroll
        for (int c = 0; c < 4; ++c) {
            const uint4 v = *(const uint4*)(xb + (size_t)idx[s][c] * 128);
            const float w = wt[s][c];
            acc[0] += bflo(v.x) * w; acc[1] += bfhi(v.x) * w;
            acc[2] += bflo(v.y) * w; acc[3] += bfhi(v.y) * w;
            acc[4] += bflo(v.z) * w; acc[5] += bfhi(v.z) * w;
            acc[6] += bflo(v.w) * w; acc[7] += bfhi(v.w) * w;
        }
    }

    uint4 o;
    o.x = (unsigned)f2bf(acc[0]) | ((unsigned)f2bf(acc[1]) << 16);
    o.y = (unsigned)f2bf(acc[2]) | ((unsigned)f2bf(acc[3]) << 16);
    o.z = (unsigned)f2bf(acc[4]) | ((unsigned)f2bf(acc[5]) << 16);
    o.w = (unsigned)f2bf(acc[6]) | ((unsigned)f2bf(acc[7]) << 16);
    *(uint4*)(sampled + (size_t)p * 128 + cl * 8) = o;
}

// ---------------------------------------------------------------------------
// Kernel 3: implicit-GEMM 3x3 conv via bf16 MFMA. m97-structure: A and B
// staged with global_load_lds dwordx4 into linear [128][BK] LDS; invalid tap
// rows DMA from the zero page instead of masking in registers.
// ---------------------------------------------------------------------------
__global__ __launch_bounds__(256) void conv_mfma_kernel(
    const unsigned short* __restrict__ sampled, const unsigned short* __restrict__ wt,
    const unsigned short* __restrict__ zbuf, float* __restrict__ out)
{
    __shared__ __align__(16) unsigned short As[128 * BK];   // 16 KB linear
    __shared__ __align__(16) unsigned short Bs[128 * BK];   // 16 KB linear

    const int tid  = threadIdx.x;
    const int lane = tid & 63;
    const int wave = tid >> 6;
    const int mb   = blockIdx.x;
    const int b    = mb / 98;
    const int p0   = (mb % 98) * 128;
    const int n0   = blockIdx.y * 128;

    // staging geometry: wave w, instr j in [0,4): rows w*32 + j*8 + (lane>>3)
    const int rlane = lane >> 3;
    const int chunk = lane & 7;

    const unsigned short* sb = sampled + (size_t)b * HW * 128;

    int py4[4], px4[4];
    const unsigned short* asrc0[4];
    const unsigned short* bsrc0[4];
#pragma unroll
    for (int j = 0; j < 4; ++j) {
        const int row = wave * 32 + j * 8 + rlane;
        const int pp  = p0 + row;
        py4[j] = pp / WW;
        px4[j] = pp % WW;
        asrc0[j] = sb + (size_t)pp * 128 + chunk * 8;
        bsrc0[j] = wt + (size_t)(n0 + row) * 1152 + chunk * 8;
    }
    const unsigned short* zsrc = zbuf + chunk * 8;

    const int col  = lane & 15;
    const int quad = lane >> 4;
    const int wm   = (wave & 1) * 64;
    const int wn   = (wave >> 1) * 64;

    f32x4 acc[4][4];
#pragma unroll
    for (int i = 0; i < 4; ++i)
#pragma unroll
        for (int j = 0; j < 4; ++j) acc[i][j] = (f32x4)0.f;

    for (int t = 0; t < 9; ++t) {
        const int dy = t / 3 - 1, dx = t % 3 - 1;
        const int tcol = t * 128;
        bool valid[4];
        const unsigned short* atv[4];
#pragma unroll
        for (int j = 0; j < 4; ++j) {
            valid[j] = ((unsigned)(py4[j] + dy) < HH) && ((unsigned)(px4[j] + dx) < WW);
            atv[j]   = asrc0[j] + (dy * WW + dx) * 128;
        }

#pragma unroll
        for (int ci0 = 0; ci0 < 128; ci0 += BK) {
            __syncthreads();   // previous frags consumed before DMA overwrites
#pragma unroll
            for (int j = 0; j < 4; ++j)
                gload16(valid[j] ? atv[j] + ci0 : zsrc, As + (wave * 32 + j * 8) * BK);
#pragma unroll
            for (int j = 0; j < 4; ++j)
                gload16(bsrc0[j] + tcol + ci0, Bs + (wave * 32 + j * 8) * BK);
            __syncthreads();   // drains vmcnt(0): all DMA landed

#pragma unroll
            for (int kk = 0; kk < BK; kk += 32) {
                short8 af[4], bf[4];
#pragma unroll
                for (int f = 0; f < 4; ++f)
                    af[f] = *(const short8*)(As + (wm + f * 16 + col) * BK + kk + quad * 8);
#pragma unroll
                for (int f = 0; f < 4; ++f)
                    bf[f] = *(const short8*)(Bs + (wn + f * 16 + col) * BK + kk + quad * 8);
#pragma unroll
                for (int fm = 0; fm < 4; ++fm)
#pragma unroll
                    for (int fn = 0; fn < 4; ++fn)
                        acc[fm][fn] = __builtin_amdgcn_mfma_f32_16x16x32_bf16(
                            af[fm], bf[fn], acc[fm][fn], 0, 0, 0);
            }
        }
    }

#pragma unroll
    for (int fm = 0; fm < 4; ++fm) {
        const int pix = p0 + wm + fm * 16 + quad * 4;
#pragma unroll
        for (int fn = 0; fn < 4; ++fn) {
            const int co = n0 + wn + fn * 16 + col;
            float* op = out + ((size_t)(b * COUT + co)) * HW + pix;
            *(f32x4*)op = acc[fm][fn];
        }
    }
}

// ---------------------------------------------------------------------------
extern "C" void kernel_launch(void* const* d_in, const int* in_sizes, int n_in,
                              void* d_out, int out_size, void* d_ws, size_t ws_size,
                              hipStream_t stream)
{
    const float* x  = (const float*)d_in[0];   // (8,128,112,112)
    const float* ow = (const float*)d_in[1];   // (18,128,3,3)
    const float* ob = (const float*)d_in[2];   // (18,)
    const float* cw = (const float*)d_in[3];   // (256,128,3,3)
    float* out = (float*)d_out;                // (8,256,112,112)

    // ws: po 3.6MB | sampled 25.7MB | wt 0.59MB | xh 25.7MB | owt 74KB | zbuf 512B
    unsigned int*   po      = (unsigned int*)d_ws;
    unsigned short* sampled = (unsigned short*)(po + (size_t)NPIX * 9);
    unsigned short* wtb     = sampled + (size_t)NPIX * 128;
    unsigned short* xh      = wtb + (size_t)COUT * 1152;
    unsigned short* owt     = xh + (size_t)NPIX * 128;
    unsigned short* zbuf    = owt + (size_t)32 * 1152;

    zfill_kernel<<<dim3(1), dim3(256), 0, stream>>>(zbuf);
    wconvert_kernel<<<dim3(1152), dim3(256), 0, stream>>>(cw, wtb);
    owconvert_kernel<<<dim3(144), dim3(256), 0, stream>>>(ow, owt);
    nhwc_kernel<<<dim3(NPIX / 64), dim3(256), 0, stream>>>(x, xh);
    offset_mfma_kernel<<<dim3(784), dim3(256), 0, stream>>>(xh, owt, ob, zbuf, po);
    sample2_kernel<<<dim3(NPIX / 16), dim3(256), 0, stream>>>(xh, po, sampled);
    conv_mfma_kernel<<<dim3(784, 2), dim3(256), 0, stream>>>(sampled, wtb, zbuf, out);
}